// Round 5
// baseline (311.990 us; speedup 1.0000x reference)
//
#include <hip/hip_runtime.h>

// QRNN fo-pooling via chunked (Blelloch-style) linear-scan decomposition.
// c_t = f_t*c_{t-1} + g_t,  g_t = (1-f_t)*tanh(z_t),  h_t = o_t*c_t
// Over a chunk: c_end = A*c_start + B, A = prod f, B = local scan of g.
// Pass1: per-chunk (A,B).  Combine: 16-step scan over chunks -> c_start per chunk.
// Pass2: replay each chunk from its known c_start, write h.

#define T_SEQ 512
#define BATCH 32
#define HID   1024
#define CH    (BATCH * HID)       // 32768 channels
#define ROWS  (BATCH * 3 * HID)   // floats per t-step of Y
#define NC    16                  // chunks
#define CL    (T_SEQ / NC)        // 32 steps per chunk

__device__ __forceinline__ float fast_sigmoid(float x) {
    float e = __builtin_amdgcn_exp2f(-1.4426950408889634f * x);
    return __builtin_amdgcn_rcpf(1.0f + e);
}
__device__ __forceinline__ float fast_tanh(float x) {
    float e = __builtin_amdgcn_exp2f(-2.8853900817779268f * x);
    float s = __builtin_amdgcn_rcpf(1.0f + e);
    return __builtin_fmaf(2.0f, s, -1.0f);
}

// ---------------- Pass 1: per-(chunk, channel) affine coefficients ----------
__global__ __launch_bounds__(64) void pass1(const float* __restrict__ Y,
                                            float* __restrict__ wsA,
                                            float* __restrict__ wsB) {
    const int ch = blockIdx.x * 64 + threadIdx.x;
    const int k  = blockIdx.y;
    const int b  = ch >> 10;
    const int h  = ch & (HID - 1);
    const float* yb = Y + b * (3 * HID) + h + (k * CL) * ROWS;

    float A = 1.0f, Bc = 0.0f;
    constexpr int PF = 8;
    float fA[PF], zA[PF], fB[PF], zB[PF];

    auto LOAD = [&](float* f, float* z, int t0) {
#pragma unroll
        for (int i = 0; i < PF; ++i) {
            const float* p = yb + (t0 + i) * ROWS;
            f[i] = p[0]; z[i] = p[HID];
        }
    };
    auto COMP = [&](float* f, float* z) {
#pragma unroll
        for (int i = 0; i < PF; ++i) {
            float ff = fast_sigmoid(f[i]);
            float g  = (1.0f - ff) * fast_tanh(z[i]);
            Bc = __builtin_fmaf(ff, Bc, g);
            A *= ff;
        }
    };

    LOAD(fA, zA, 0);
    LOAD(fB, zB, PF);
    COMP(fA, zA);
    LOAD(fA, zA, 2 * PF);
    COMP(fB, zB);
    LOAD(fB, zB, 3 * PF);
    COMP(fA, zA);
    COMP(fB, zB);

    wsA[k * CH + ch] = A;
    wsB[k * CH + ch] = Bc;
}

// ---------------- Combine: 16-step scan over chunk coefficients ------------
__global__ __launch_bounds__(64) void combine(const float* __restrict__ wsA,
                                              const float* __restrict__ wsB,
                                              const float* __restrict__ init_c,
                                              const float* __restrict__ init_h,
                                              float* __restrict__ cstart,
                                              float* __restrict__ out) {
    const int ch = blockIdx.x * 64 + threadIdx.x;
    out[ch] = init_h[ch];                    // output row 0

    float Av[NC], Bv[NC];
#pragma unroll
    for (int k = 0; k < NC; ++k) {           // all loads independent -> one batch
        Av[k] = wsA[k * CH + ch];
        Bv[k] = wsB[k * CH + ch];
    }
    float c = init_c[ch];
#pragma unroll
    for (int k = 0; k < NC; ++k) {
        cstart[k * CH + ch] = c;
        c = __builtin_fmaf(Av[k], c, Bv[k]);
    }
}

// ---------------- Pass 2: replay chunks with known c_start -----------------
__global__ __launch_bounds__(64) void pass2(const float* __restrict__ Y,
                                            const float* __restrict__ cstart,
                                            float* __restrict__ out) {
    const int ch = blockIdx.x * 64 + threadIdx.x;
    const int k  = blockIdx.y;
    const int b  = ch >> 10;
    const int h  = ch & (HID - 1);
    const float* yb = Y + b * (3 * HID) + h + (k * CL) * ROWS;
    float* ob = out + (k * CL + 1) * CH + ch;

    float c = cstart[k * CH + ch];
    constexpr int PF = 8;
    float fA[PF], zA[PF], oA[PF], fB[PF], zB[PF], oB[PF];

    auto LOAD = [&](float* f, float* z, float* o, int t0) {
#pragma unroll
        for (int i = 0; i < PF; ++i) {
            const float* p = yb + (t0 + i) * ROWS;
            f[i] = p[0]; z[i] = p[HID]; o[i] = p[2 * HID];
        }
    };
    auto COMP = [&](float* f, float* z, float* o, int t0) {
#pragma unroll
        for (int i = 0; i < PF; ++i) {
            float ff = fast_sigmoid(f[i]);
            float g  = (1.0f - ff) * fast_tanh(z[i]);
            float oo = fast_sigmoid(o[i]);
            c = __builtin_fmaf(ff, c, g);
            ob[(t0 + i) * CH] = c * oo;
        }
    };

    LOAD(fA, zA, oA, 0);
    LOAD(fB, zB, oB, PF);
    COMP(fA, zA, oA, 0);
    LOAD(fA, zA, oA, 2 * PF);
    COMP(fB, zB, oB, PF);
    LOAD(fB, zB, oB, 3 * PF);
    COMP(fA, zA, oA, 2 * PF);
    COMP(fB, zB, oB, 3 * PF);
}

extern "C" void kernel_launch(void* const* d_in, const int* in_sizes, int n_in,
                              void* d_out, int out_size, void* d_ws, size_t ws_size,
                              hipStream_t stream) {
    const float* Y      = (const float*)d_in[0];
    const float* init_c = (const float*)d_in[1];
    const float* init_h = (const float*)d_in[2];
    float* out = (float*)d_out;

    float* wsA    = (float*)d_ws;            // [NC][CH]
    float* wsB    = wsA + NC * CH;           // [NC][CH]
    float* cstart = wsB + NC * CH;           // [NC][CH]  (6 MB total)

    dim3 grid(CH / 64, NC);
    pass1<<<grid, 64, 0, stream>>>(Y, wsA, wsB);
    combine<<<CH / 64, 64, 0, stream>>>(wsA, wsB, init_c, init_h, cstart, out);
    pass2<<<grid, 64, 0, stream>>>(Y, cstart, out);
}

// Round 6
// 310.162 us; speedup vs baseline: 1.0059x; 1.0059x over previous
//
#include <hip/hip_runtime.h>

// QRNN fo-pooling via chunked linear-scan decomposition, float4-vectorized.
// c_t = f*c_{t-1} + g, g = (1-f)*tanh(z), h_t = o*c_t  (f,o = sigmoid of raw)
// Pass1: per-chunk affine (A,B).  Combine: scan over chunks -> c_start.
// Pass2: replay chunks from known c_start, write h.

#define T_SEQ 512
#define BATCH 32
#define HID   1024
#define CH    (BATCH * HID)        // 32768 channels
#define CH4   (CH / 4)             // 8192 float4 lanes
#define HID4  (HID / 4)            // 256
#define ROWS4 (BATCH * 3 * HID4)   // 24576 float4 per t-step of Y
#define NC    32                   // chunks
#define CL    (T_SEQ / NC)         // 16 steps per chunk

__device__ __forceinline__ float fast_sigmoid(float x) {
    float e = __builtin_amdgcn_exp2f(-1.4426950408889634f * x);
    return __builtin_amdgcn_rcpf(1.0f + e);
}
__device__ __forceinline__ float fast_tanh(float x) {
    float e = __builtin_amdgcn_exp2f(-2.8853900817779268f * x);
    float s = __builtin_amdgcn_rcpf(1.0f + e);
    return __builtin_fmaf(2.0f, s, -1.0f);
}

__device__ __forceinline__ void step1(float f, float z, float& A, float& B) {
    float ff = fast_sigmoid(f);
    float g  = (1.0f - ff) * fast_tanh(z);
    B = __builtin_fmaf(ff, B, g);
    A *= ff;
}
__device__ __forceinline__ float step2(float f, float z, float o, float& c) {
    float ff = fast_sigmoid(f);
    float g  = (1.0f - ff) * fast_tanh(z);
    c = __builtin_fmaf(ff, c, g);
    return c * fast_sigmoid(o);
}

// ---------------- Pass 1: per-(chunk, channel4) affine coefficients --------
__global__ __launch_bounds__(256, 4) void pass1(const float4* __restrict__ Y4,
                                                float4* __restrict__ wsA,
                                                float4* __restrict__ wsB) {
    const int c4 = blockIdx.x * 256 + threadIdx.x;   // [0, CH4)
    const int k  = blockIdx.y;
    const int b  = c4 >> 8;             // / HID4
    const int h4 = c4 & (HID4 - 1);
    const float4* yb = Y4 + b * (3 * HID4) + h4 + (size_t)(k * CL) * ROWS4;

    float4 A = make_float4(1.f, 1.f, 1.f, 1.f);
    float4 B = make_float4(0.f, 0.f, 0.f, 0.f);

    float4 f0 = yb[0], z0 = yb[HID4];
#pragma unroll
    for (int t = 0; t < CL; ++t) {
        float4 f1, z1;
        if (t + 1 < CL) {                 // rolling prefetch of next t-step
            const float4* p = yb + (size_t)(t + 1) * ROWS4;
            f1 = p[0]; z1 = p[HID4];
        }
        step1(f0.x, z0.x, A.x, B.x);
        step1(f0.y, z0.y, A.y, B.y);
        step1(f0.z, z0.z, A.z, B.z);
        step1(f0.w, z0.w, A.w, B.w);
        f0 = f1; z0 = z1;
    }
    wsA[(size_t)k * CH4 + c4] = A;
    wsB[(size_t)k * CH4 + c4] = B;
}

// ---------------- Combine: NC-step scan over chunk coefficients ------------
__global__ __launch_bounds__(256) void combine(const float* __restrict__ wsA,
                                               const float* __restrict__ wsB,
                                               const float* __restrict__ init_c,
                                               const float* __restrict__ init_h,
                                               float* __restrict__ cstart,
                                               float* __restrict__ out) {
    const int ch = blockIdx.x * 256 + threadIdx.x;   // [0, CH)
    out[ch] = init_h[ch];                            // output row 0

    float Av[NC], Bv[NC];                            // fully unrolled -> registers
#pragma unroll
    for (int k = 0; k < NC; ++k) {
        Av[k] = wsA[(size_t)k * CH + ch];
        Bv[k] = wsB[(size_t)k * CH + ch];
    }
    float c = init_c[ch];
#pragma unroll
    for (int k = 0; k < NC; ++k) {
        cstart[(size_t)k * CH + ch] = c;
        c = __builtin_fmaf(Av[k], c, Bv[k]);
    }
}

// ---------------- Pass 2: replay chunks with known c_start -----------------
__global__ __launch_bounds__(256, 4) void pass2(const float4* __restrict__ Y4,
                                                const float4* __restrict__ cstart4,
                                                float4* __restrict__ out4) {
    const int c4 = blockIdx.x * 256 + threadIdx.x;
    const int k  = blockIdx.y;
    const int b  = c4 >> 8;
    const int h4 = c4 & (HID4 - 1);
    const float4* yb = Y4 + b * (3 * HID4) + h4 + (size_t)(k * CL) * ROWS4;
    float4* ob = out4 + (size_t)(k * CL + 1) * CH4 + c4;

    float4 c = cstart4[(size_t)k * CH4 + c4];

    float4 f0 = yb[0], z0 = yb[HID4], o0 = yb[2 * HID4];
#pragma unroll
    for (int t = 0; t < CL; ++t) {
        float4 f1, z1, o1;
        if (t + 1 < CL) {
            const float4* p = yb + (size_t)(t + 1) * ROWS4;
            f1 = p[0]; z1 = p[HID4]; o1 = p[2 * HID4];
        }
        float4 hh;
        hh.x = step2(f0.x, z0.x, o0.x, c.x);
        hh.y = step2(f0.y, z0.y, o0.y, c.y);
        hh.z = step2(f0.z, z0.z, o0.z, c.z);
        hh.w = step2(f0.w, z0.w, o0.w, c.w);
        ob[(size_t)t * CH4] = hh;
        f0 = f1; z0 = z1; o0 = o1;
    }
}

extern "C" void kernel_launch(void* const* d_in, const int* in_sizes, int n_in,
                              void* d_out, int out_size, void* d_ws, size_t ws_size,
                              hipStream_t stream) {
    const float* Y      = (const float*)d_in[0];
    const float* init_c = (const float*)d_in[1];
    const float* init_h = (const float*)d_in[2];
    float* out = (float*)d_out;

    float* wsA    = (float*)d_ws;                 // [NC][CH] floats (4.2 MB)
    float* wsB    = wsA + (size_t)NC * CH;        // [NC][CH]
    float* cstart = wsB + (size_t)NC * CH;        // [NC][CH]

    dim3 grid(CH4 / 256, NC);                     // (32, 32) = 1024 blocks
    pass1<<<grid, 256, 0, stream>>>((const float4*)Y, (float4*)wsA, (float4*)wsB);
    combine<<<CH / 256, 256, 0, stream>>>(wsA, wsB, init_c, init_h, cstart, out);
    pass2<<<grid, 256, 0, stream>>>((const float4*)Y, (const float4*)cstart, (float4*)out);
}

// Round 7
// 306.643 us; speedup vs baseline: 1.0174x; 1.0115x over previous
//
#include <hip/hip_runtime.h>

// QRNN fo-pooling, single fused kernel.
// c_t = ff*c_{t-1} + gg, ff = sigmoid(F), gg = (1-ff)*tanh(Z), h_t = sigmoid(O)*c_t
// Chunked linear scan INSIDE one block: 64 chunks x 8 steps cover T=512.
// Phase 1: each thread computes its chunk's affine (A,B) over 4 channels,
//          retaining ff,gg per step in registers (no re-read of F,Z).
// Combine: 16 threads scan the 64 chunks in LDS -> per-chunk c_start.
// Phase 2: replay from registers, loading only O (first touch), write h.

#define T_SEQ 512
#define BATCH 32
#define HID   1024
#define CH    (BATCH * HID)        // 32768 channels
#define CH4   (CH / 4)             // 8192 float4 groups
#define HID4  (HID / 4)            // 256
#define ROWS4 (BATCH * 3 * HID4)   // float4 per t-step of Y
#define NC    64                   // chunks (within one block)
#define CL    (T_SEQ / NC)         // 8 steps per chunk
#define JW    16                   // float4 channel-groups per block
#define NTHR  (NC * JW)            // 1024 threads

__device__ __forceinline__ float fast_sigmoid(float x) {
    float e = __builtin_amdgcn_exp2f(-1.4426950408889634f * x);
    return __builtin_amdgcn_rcpf(1.0f + e);
}
__device__ __forceinline__ float fast_tanh(float x) {
    float e = __builtin_amdgcn_exp2f(-2.8853900817779268f * x);
    float s = __builtin_amdgcn_rcpf(1.0f + e);
    return __builtin_fmaf(2.0f, s, -1.0f);
}
__device__ __forceinline__ float4 sig4(float4 v) {
    return make_float4(fast_sigmoid(v.x), fast_sigmoid(v.y),
                       fast_sigmoid(v.z), fast_sigmoid(v.w));
}
__device__ __forceinline__ float4 tanh4(float4 v) {
    return make_float4(fast_tanh(v.x), fast_tanh(v.y),
                       fast_tanh(v.z), fast_tanh(v.w));
}

__global__ __launch_bounds__(NTHR, 4) void fo_pool_fused(
        const float4* __restrict__ Y4,
        const float4* __restrict__ init_c4,
        const float4* __restrict__ init_h4,
        float4* __restrict__ out4) {
    __shared__ float4 sA[NC][JW];   // chunk A; overwritten with c_start in combine
    __shared__ float4 sB[NC][JW];   // chunk B

    const int tid = threadIdx.x;
    const int k   = tid >> 4;            // chunk index [0,64)
    const int j   = tid & (JW - 1);      // channel-group within block [0,16)
    const int c4  = blockIdx.x * JW + j; // global float4 channel group
    const int b   = c4 >> 8;             // / HID4
    const int h4  = c4 & (HID4 - 1);
    const float4* yb = Y4 + b * (3 * HID4) + h4 + (size_t)(k * CL) * ROWS4;

    // ---------------- Phase 1: chunk-local affine, retain ff/gg ------------
    float4 ff[CL], gg[CL];
    float4 A = make_float4(1.f, 1.f, 1.f, 1.f);
    float4 B = make_float4(0.f, 0.f, 0.f, 0.f);

    float4 f0 = yb[0], z0 = yb[HID4];
#pragma unroll
    for (int t = 0; t < CL; ++t) {
        float4 f1, z1;
        if (t + 1 < CL) {
            const float4* p = yb + (size_t)(t + 1) * ROWS4;
            f1 = p[0]; z1 = p[HID4];
        }
        float4 s  = sig4(f0);
        float4 th = tanh4(z0);
        float4 g  = make_float4((1.f - s.x) * th.x, (1.f - s.y) * th.y,
                                (1.f - s.z) * th.z, (1.f - s.w) * th.w);
        ff[t] = s; gg[t] = g;
        B.x = __builtin_fmaf(s.x, B.x, g.x);
        B.y = __builtin_fmaf(s.y, B.y, g.y);
        B.z = __builtin_fmaf(s.z, B.z, g.z);
        B.w = __builtin_fmaf(s.w, B.w, g.w);
        A.x *= s.x; A.y *= s.y; A.z *= s.z; A.w *= s.w;
        f0 = f1; z0 = z1;
    }
    sA[k][j] = A;
    sB[k][j] = B;
    __syncthreads();

    // ---------------- Combine: serial scan over 64 chunks (16 threads) -----
    if (tid < JW) {
        const int cc4 = blockIdx.x * JW + tid;
        out4[cc4] = init_h4[cc4];               // output row 0
        float4 c = init_c4[cc4];
#pragma unroll
        for (int kk = 0; kk < NC; ++kk) {
            float4 a  = sA[kk][tid];
            float4 b0 = sB[kk][tid];
            sA[kk][tid] = c;                    // c_start for chunk kk
            c.x = __builtin_fmaf(a.x, c.x, b0.x);
            c.y = __builtin_fmaf(a.y, c.y, b0.y);
            c.z = __builtin_fmaf(a.z, c.z, b0.z);
            c.w = __builtin_fmaf(a.w, c.w, b0.w);
        }
    }
    __syncthreads();

    // ---------------- Phase 2: replay from registers, load only O ----------
    float4 c = sA[k][j];
    float4* ob = out4 + (size_t)(k * CL + 1) * CH4 + c4;

    float4 o0 = yb[2 * HID4];
#pragma unroll
    for (int t = 0; t < CL; ++t) {
        float4 o1;
        if (t + 1 < CL) o1 = (yb + (size_t)(t + 1) * ROWS4)[2 * HID4];
        c.x = __builtin_fmaf(ff[t].x, c.x, gg[t].x);
        c.y = __builtin_fmaf(ff[t].y, c.y, gg[t].y);
        c.z = __builtin_fmaf(ff[t].z, c.z, gg[t].z);
        c.w = __builtin_fmaf(ff[t].w, c.w, gg[t].w);
        float4 oo = sig4(o0);
        float4 hh = make_float4(c.x * oo.x, c.y * oo.y, c.z * oo.z, c.w * oo.w);
        ob[(size_t)t * CH4] = hh;
        o0 = o1;
    }
}

extern "C" void kernel_launch(void* const* d_in, const int* in_sizes, int n_in,
                              void* d_out, int out_size, void* d_ws, size_t ws_size,
                              hipStream_t stream) {
    const float* Y      = (const float*)d_in[0];
    const float* init_c = (const float*)d_in[1];
    const float* init_h = (const float*)d_in[2];
    float* out = (float*)d_out;

    // 512 blocks x 1024 threads; each block owns 64 channels across all T.
    fo_pool_fused<<<CH4 / JW, NTHR, 0, stream>>>(
        (const float4*)Y, (const float4*)init_c, (const float4*)init_h, (float4*)out);
}